// Round 8
// baseline (109.538 us; speedup 1.0000x reference)
//
#include <hip/hip_runtime.h>

#define NBATCH 256

typedef __attribute__((ext_vector_type(8))) short bf16x8;
typedef __attribute__((ext_vector_type(4))) float f32x4;

__device__ __forceinline__ unsigned short f2b(float f) {
    unsigned u = __float_as_uint(f);
    u = (u + 0x7fffu + ((u >> 16) & 1u)) >> 16;
    return (unsigned short)u;
}
__device__ __forceinline__ float b2f(unsigned short h) {
    return __uint_as_float(((unsigned)h) << 16);
}
__device__ __forceinline__ void async16(const void* g, void* l) {
    __builtin_amdgcn_global_load_lds((const __attribute__((address_space(1))) unsigned int*)g,
                                     (__attribute__((address_space(3))) unsigned int*)l, 16, 0, 0);
}

// ---------------- fused prep kernel (x4 vectorized, round-6 tiling) ----------------
// blocks [0,512): W0 ; [512,1536): W1 ; [1536,2560): W2 ; [2560,3584): x
// W tiling: granule per (rg, kstep): [kseg(4)][l15(16)][j(8)]; kstep = f*NCS + cs.
__global__ void prep_all(const float* __restrict__ x,
                         const float* __restrict__ W0,
                         const float* __restrict__ W1,
                         const float* __restrict__ W2,
                         unsigned short* __restrict__ x0t,
                         unsigned short* __restrict__ x0f,
                         unsigned short* __restrict__ Wp0,
                         unsigned short* __restrict__ Wp1,
                         unsigned short* __restrict__ Wp2)
{
    const int bid = blockIdx.x, tid = threadIdx.x;
    if (bid < 2560) {
        const float* W; unsigned short* Wp; int CLOG, KLOG, lbid;
        if (bid < 512)       { W = W0; Wp = Wp0; CLOG = 6; KLOG = 12; lbid = bid; }
        else if (bid < 1536) { W = W1; Wp = Wp1; CLOG = 7; KLOG = 13; lbid = bid - 512; }
        else                 { W = W2; Wp = Wp2; CLOG = 7; KLOG = 13; lbid = bid - 1536; }
        const int base = (lbid * 256 + tid) * 4;   // 4 consecutive k, same o
        int o = base >> KLOG, k = base & ((1 << KLOG) - 1);
        int f = k >> CLOG, c = k & ((1 << CLOG) - 1);
        int rg = o >> 4, l15 = o & 15;
        int cs = c >> 5, kseg = (c >> 3) & 3, j = c & 7;   // j aligned to 4
        int NCS = 1 << (CLOG - 5);
        int NK = 64 * NCS;
        int kstep = f * NCS + cs;
        size_t dst = (((size_t)rg * NK + kstep) * 64 + kseg * 16 + l15) * 8 + j;
        const float4 wv = *(const float4*)(W + base);
        *(ushort4*)(Wp + dst) = make_ushort4(f2b(wv.x), f2b(wv.y), f2b(wv.z), f2b(wv.w));
    } else {
        const int base = ((bid - 2560) * 256 + tid) * 4;   // 4 consecutive e
        int b = base >> 12, r = base & 4095, f = r >> 6, e0 = r & 63;
        const float4 xv = *(const float4*)(x + base);
        ushort4 v = make_ushort4(f2b(xv.x), f2b(xv.y), f2b(xv.z), f2b(xv.w));
        *(ushort4*)(x0f + b * 4096 + f * 64 + e0) = v;     // [b][f][e]
        x0t[b * 4096 + (e0 + 0) * 64 + f] = v.x;           // [b][e][f]
        x0t[b * 4096 + (e0 + 1) * 64 + f] = v.y;
        x0t[b * 4096 + (e0 + 2) * 64 + f] = v.z;
        x0t[b * 4096 + (e0 + 3) * 64 + f] = v.w;
    }
}

// ---------------- per-layer GEMM kernel ----------------
// grid 512 = 8 rg (16 o-rows, XCD-affine) x 64 sgg (4 samples); 512 thr, 8 waves.
// wave w: sample p = w&3 (s = sgg*4+p), kg = w>>2 (c-half split).
// A: streams global->VGPR 2-field register ring (W rg-slice is L2-resident/XCD).
// B: xk granules for this wave's c-half, VGPR-resident + asm-pinned.
// x0 fold scales from per-sample LDS; cross-kg LDS reduce at layer end.
// No barriers in the k-loop.
template <int CL, bool LAST>
__global__ __launch_bounds__(512, 2) void layer_k(
    const unsigned short* __restrict__ Wp,    // pre-tiled A, rg-sliced
    const unsigned short* __restrict__ Bsrc,  // [b][e][c] rows of CL*2 bytes
    const unsigned short* __restrict__ x0f,   // [b][f][e]
    const float* __restrict__ Wa_l,
    unsigned short* __restrict__ xknext,      // [b][e][o] rows of 256B
    float* __restrict__ ybuf)                 // [256][8] this layer
{
    constexpr int NCS  = CL / 32;             // total cs granules (2 or 4)
    constexpr int NCS2 = NCS / 2;             // per-wave cs granules (1 or 2)
    constexpr int NK   = 64 * NCS;            // total ksteps in rg slice
    __shared__ char sm[49152];
    char* smX = sm;            // 4 x 8 KB per-sample x0f
    char* smR = sm + 32768;    // 16 KB cross-kg reduce

    const int bid = blockIdx.x, tid = threadIdx.x;
    const int rg = bid & 7, sgg = bid >> 3;
    const int lane = tid & 63, w = tid >> 6;
    const int p = w & 3, kg = w >> 2;
    const int s = sgg * 4 + p;
    const int l15 = lane & 15, kseg = lane >> 4;

    // stage 4 samples' x0f (8 KB each): wave w covers 1KB per sample
#pragma unroll
    for (int q = 0; q < 4; ++q)
        async16((const char*)x0f + (size_t)(sgg * 4 + q) * 8192 + w * 1024 + lane * 16,
                smX + q * 8192 + w * 1024);

    // B granules for this wave's c-half: load once, VGPR-resident
    bf16x8 bq[NCS2][4];
    {
        const char* Bb = (const char*)Bsrc + (size_t)s * (CL * 128) + kseg * 16;
#pragma unroll
        for (int i = 0; i < NCS2; ++i)
#pragma unroll
            for (int nt = 0; nt < 4; ++nt)
                bq[i][nt] = *(const bf16x8*)(Bb + (nt * 16 + l15) * (CL * 2)
                                             + (kg * NCS2 + i) * 64);
    }

    const char* Ag = (const char*)Wp + (size_t)rg * NK * 1024 + (kseg * 16 + l15) * 16;
#define LD_A(dst, f) { _Pragma("unroll") for (int i_ = 0; i_ < NCS2; ++i_) \
    dst[i_] = *(const bf16x8*)(Ag + (size_t)((f) * NCS + kg * NCS2 + i_) * 1024); }

    bf16x8 aqA[NCS2], aqB[NCS2];
    LD_A(aqA, 0);

    __syncthreads();   // x0f staging complete

    const unsigned short* XS = (const unsigned short*)(smX + p * 8192);
    const f32x4 ZERO = {0.f, 0.f, 0.f, 0.f};
    f32x4 acc[4], accf[4];
#pragma unroll
    for (int nt = 0; nt < 4; ++nt) acc[nt] = ZERO;

#define CONSUME(A, f) { \
    const float sv0 = b2f(XS[(f) * 64 + l15]); \
    const float sv1 = b2f(XS[(f) * 64 + 16 + l15]); \
    const float sv2 = b2f(XS[(f) * 64 + 32 + l15]); \
    const float sv3 = b2f(XS[(f) * 64 + 48 + l15]); \
    _Pragma("unroll") for (int i_ = 0; i_ < NCS2; ++i_) { \
        _Pragma("unroll") for (int nt_ = 0; nt_ < 4; ++nt_) \
            accf[nt_] = __builtin_amdgcn_mfma_f32_16x16x32_bf16( \
                A[i_], bq[i_][nt_], (i_ == 0) ? ZERO : accf[nt_], 0, 0, 0); \
    } \
    acc[0] += accf[0] * f32x4{sv0, sv0, sv0, sv0}; \
    acc[1] += accf[1] * f32x4{sv1, sv1, sv1, sv1}; \
    acc[2] += accf[2] * f32x4{sv2, sv2, sv2, sv2}; \
    acc[3] += accf[3] * f32x4{sv3, sv3, sv3, sv3}; }

    for (int ch = 0; ch < 8; ++ch) {
        // pin bq (prevents the compiler sinking B loads into the loop)
#pragma unroll
        for (int i = 0; i < NCS2; ++i)
            asm volatile("" :: "v"(bq[i][0]), "v"(bq[i][1]), "v"(bq[i][2]), "v"(bq[i][3]));
#pragma unroll
        for (int fi = 0; fi < 8; ++fi) {
            const int f = ch * 8 + fi;
            if ((fi & 1) == 0) {
                LD_A(aqB, f + 1);
                CONSUME(aqA, f);
            } else {
                if (f < 63) LD_A(aqA, f + 1);
                CONSUME(aqB, f);
            }
        }
    }
#undef LD_A
#undef CONSUME

    // ---- cross-kg reduction ----
    if (kg == 1) {
#pragma unroll
        for (int nt = 0; nt < 4; ++nt)
            *(f32x4*)(smR + p * 4096 + lane * 64 + nt * 16) = acc[nt];
    }
    __syncthreads();
    if (kg == 0) {
#pragma unroll
        for (int nt = 0; nt < 4; ++nt)
            acc[nt] += *(const f32x4*)(smR + p * 4096 + lane * 64 + nt * 16);

        // epilogue: relu, y-partial, xknext write (round-6 validated mapping)
        const float4 wa = *(const float4*)(Wa_l + rg * 16 + kseg * 4);
        float ypart = 0.f;
#pragma unroll
        for (int nt = 0; nt < 4; ++nt) {
            f32x4 v = acc[nt];
            v.x = fmaxf(v.x, 0.f); v.y = fmaxf(v.y, 0.f);
            v.z = fmaxf(v.z, 0.f); v.w = fmaxf(v.w, 0.f);
            ypart = fmaf(wa.x, v.x, ypart);
            ypart = fmaf(wa.y, v.y, ypart);
            ypart = fmaf(wa.z, v.z, ypart);
            ypart = fmaf(wa.w, v.w, ypart);
            if (!LAST) {
                unsigned lo = (unsigned)f2b(v.x) | ((unsigned)f2b(v.y) << 16);
                unsigned hi = (unsigned)f2b(v.z) | ((unsigned)f2b(v.w) << 16);
                *(uint2*)((char*)xknext + (size_t)s * 16384 + (nt * 16 + l15) * 256
                          + (rg * 16 + kseg * 4) * 2) = make_uint2(lo, hi);
            }
        }
#pragma unroll
        for (int off = 32; off >= 1; off >>= 1)
            ypart += __shfl_down(ypart, off, 64);
        if (lane == 0) ybuf[s * 8 + rg] = ypart;
    }
}

__global__ void finalize_k(const float* __restrict__ ybuf, float* __restrict__ y) {
    const int b = threadIdx.x;
    float sum = 0.f;
#pragma unroll
    for (int l = 0; l < 3; ++l)
#pragma unroll
        for (int r = 0; r < 8; ++r)
            sum += ybuf[l * 2048 + b * 8 + r];
    y[b] = sum;
}

extern "C" void kernel_launch(void* const* d_in, const int* in_sizes, int n_in,
                              void* d_out, int out_size, void* d_ws, size_t ws_size,
                              hipStream_t stream) {
    const float* x  = (const float*)d_in[0];
    const float* W0 = (const float*)d_in[1];
    const float* W1 = (const float*)d_in[2];
    const float* W2 = (const float*)d_in[3];
    const float* Wa = (const float*)d_in[4];
    float* y = (float*)d_out;

    char* ws = (char*)d_ws;
    unsigned short* Wp0  = (unsigned short*)(ws + 0x000000);   // 1MB (+pad)
    unsigned short* Wp1  = (unsigned short*)(ws + 0x110000);   // 2MB (+pad)
    unsigned short* Wp2  = (unsigned short*)(ws + 0x320000);   // 2MB (+pad)
    unsigned short* x0t  = (unsigned short*)(ws + 0x530000);   // 2MB
    unsigned short* x0f  = (unsigned short*)(ws + 0x730000);   // 2MB
    unsigned short* xkA  = (unsigned short*)(ws + 0x930000);   // 4MB
    unsigned short* xkB  = (unsigned short*)(ws + 0xD30000);   // 4MB
    float*          ybuf = (float*)(ws + 0x1130000);           // 24KB

    hipLaunchKernelGGL(prep_all, dim3(3584), dim3(256), 0, stream,
                       x, W0, W1, W2, x0t, x0f, Wp0, Wp1, Wp2);

    hipLaunchKernelGGL((layer_k<64, false>), dim3(512), dim3(512), 0, stream,
                       Wp0, x0t, x0f, Wa + 0, xkA, ybuf + 0);
    hipLaunchKernelGGL((layer_k<128, false>), dim3(512), dim3(512), 0, stream,
                       Wp1, xkA, x0f, Wa + 128, xkB, ybuf + 2048);
    hipLaunchKernelGGL((layer_k<128, true>), dim3(512), dim3(512), 0, stream,
                       Wp2, xkB, x0f, Wa + 256, xkA, ybuf + 4096);

    hipLaunchKernelGGL(finalize_k, dim3(1), dim3(256), 0, stream, ybuf, y);
}